// Round 4
// baseline (13724.623 us; speedup 1.0000x reference)
//
#include <hip/hip_runtime.h>

// ---------------- naive VALU GEMM: C[R x ncols] = A[R x K] * B (natural layout B[k*ldb+c])
// block = (32,8): 32 cols x 8 rows per block.
__global__ void gemm_naive(const float* __restrict__ A, int lda,
                           const float* __restrict__ B, int ldb,
                           const float* __restrict__ bias,
                           float* __restrict__ C, int ldc,
                           int R, int K, int ncols, int relu,
                           const float* __restrict__ scale_ptr)
{
    int c = blockIdx.x * 32 + threadIdx.x;
    int r = blockIdx.y * 8 + threadIdx.y;
    if (r >= R || c >= ncols) return;
    const float* a = A + (long)r * lda;
    float acc = 0.f;
    for (int k = 0; k < K; ++k) acc += a[k] * B[(long)k * ldb + c];
    if (scale_ptr) acc *= *scale_ptr;
    if (bias) acc += bias[c];
    if (relu && acc < 0.f) acc = 0.f;
    C[(long)r * ldc + c] = acc;
}

// ---------------- readout: out[r,c] = bias[c] + res.W[0:100] + T.W[100:200] + xloc.W[200:456]
// res lives in t cols 200..299, T in t cols 100..199 (ld = 300). W is (456 x dou).
__global__ void readout_kernel(const float* __restrict__ t,
                               const float* __restrict__ xloc,
                               const float* __restrict__ W,
                               const float* __restrict__ bias,
                               float* __restrict__ out, int dou, int R, int relu)
{
    int c = blockIdx.x * 32 + threadIdx.x;
    int r = blockIdx.y * 8 + threadIdx.y;
    if (r >= R || c >= dou) return;
    float acc = bias[c];
    const float* tr = t + (long)r * 300;
    for (int k = 0; k < 100; ++k) acc += tr[200 + k] * W[(long)k * dou + c];          // res part
    for (int k = 0; k < 100; ++k) acc += tr[100 + k] * W[(long)(100 + k) * dou + c];  // T part
    const float* xr = xloc + (long)r * 256;
    for (int k = 0; k < 256; ++k) acc += xr[k] * W[(long)(200 + k) * dou + c];        // local part
    if (relu && acc < 0.f) acc = 0.f;
    out[(long)r * dou + c] = acc;
}

// ---------------- CSR build
__global__ void hist_kernel(const int* __restrict__ dst, int E, int* __restrict__ cnt)
{
    int e = blockIdx.x * 256 + threadIdx.x;
    if (e < E) atomicAdd(&cnt[dst[e]], 1);
}

__global__ __launch_bounds__(1024) void scan_kernel(const int* __restrict__ cnt, int n,
                                                    int* __restrict__ rowptr,
                                                    int* __restrict__ cursor,
                                                    float* __restrict__ dis)
{
    __shared__ int sdata[1024];
    __shared__ int s_off;
    int t = threadIdx.x;
    if (t == 0) s_off = 0;
    __syncthreads();
    for (int base = 0; base < n; base += 1024) {
        int i = base + t;
        int v = (i < n) ? cnt[i] : 0;
        sdata[t] = v;
        __syncthreads();
        for (int d = 1; d < 1024; d <<= 1) {
            int x = (t >= d) ? sdata[t - d] : 0;
            __syncthreads();
            sdata[t] += x;
            __syncthreads();
        }
        int inc = sdata[t];          // inclusive scan of this chunk
        int off = s_off;
        if (i < n) {
            int excl = off + inc - v;
            rowptr[i] = excl;
            cursor[i] = excl;
            dis[i] = rsqrtf((float)(v + 1));   // deg = in-degree + self-loop
        }
        __syncthreads();
        if (t == 1023) s_off = off + inc;
        __syncthreads();
    }
    if (t == 0) rowptr[n] = s_off;
}

__global__ void scatter_kernel(const int* __restrict__ src, const int* __restrict__ dst,
                               int E, int* __restrict__ cursor, int* __restrict__ colidx)
{
    int e = blockIdx.x * 256 + threadIdx.x;
    if (e < E) {
        int d = dst[e];
        int pos = atomicAdd(&cursor[d], 1);
        colidx[pos] = src[e];
    }
}

// ---------------- GCN aggregation: one wave per dst node, lane covers 4 channels
__global__ __launch_bounds__(256) void agg_kernel(
    const float* __restrict__ h, const int* __restrict__ rowptr,
    const int* __restrict__ colidx, const float* __restrict__ dis,
    const float* __restrict__ cb, float* __restrict__ out, int ldc, int R)
{
    int wid = threadIdx.x >> 6, lane = threadIdx.x & 63;
    int i = blockIdx.x * 4 + wid;
    if (i >= R) return;
    float disi = dis[i];
    const float* hi = h + (long)i * 256;
    float acc[4];
#pragma unroll
    for (int j = 0; j < 4; ++j) acc[j] = hi[lane + j * 64] * disi;  // self loop
    int e0 = rowptr[i], e1 = rowptr[i + 1];
    for (int e = e0; e < e1; ++e) {
        int s = colidx[e];
        float w = dis[s];
        const float* hs = h + (long)s * 256;
#pragma unroll
        for (int j = 0; j < 4; ++j) acc[j] += hs[lane + j * 64] * w;
    }
#pragma unroll
    for (int j = 0; j < 4; ++j) {
        int ch = lane + j * 64;
        float v = acc[j] * disi + cb[ch];
        if (v < 0.f) v = 0.f;
        out[(long)i * ldc + ch] = v;
    }
}

// ---------------- column sums of U (t cols 0..99) and V (t cols 100..199)
__global__ void colsum_kernel(const float* __restrict__ t, int ld, int R, float* __restrict__ cs)
{
    int c = threadIdx.x;
    if (c >= 200) return;
    int i0 = blockIdx.x * 256;
    int i1 = i0 + 256; if (i1 > R) i1 = R;
    float s = 0.f;
    for (int i = i0; i < i1; ++i) s += t[(long)i * ld + c];
    atomicAdd(&cs[c], s);
}

__global__ void nf_kernel(const float* __restrict__ cs, float* __restrict__ scale, int R)
{
    __shared__ float s[128];
    int t = threadIdx.x;
    float v = (t < 100) ? cs[t] * cs[100 + t] : 0.f;
    s[t] = v;
    __syncthreads();
    for (int d = 64; d > 0; d >>= 1) {
        if (t < d) s[t] += s[t + d];
        __syncthreads();
    }
    if (t == 0) scale[0] = 1.0f / (s[0] / (float)R + 1e-6f);
}

// ---------------- M = V^T Z (100x100 fp32); V = t cols 100..199, Z = t cols 200..299 (ld=300)
__global__ __launch_bounds__(256) void vtz_kernel(const float* __restrict__ t, int ld, int R,
                                                  float* __restrict__ M)
{
    __shared__ float lds[16 * 200 + 16];
    int tid = threadIdx.x;
    int ta = tid >> 4, tb = tid & 15;
    int a0 = ta * 7, b0 = tb * 7;
    float acc[7][7] = {};
    for (long base = (long)blockIdx.x * 16; base < R; base += (long)gridDim.x * 16) {
        int nrows = (int)((R - base) < 16 ? (R - base) : 16);
        __syncthreads();
        for (int idx = tid; idx < nrows * 200; idx += 256) {
            int r = idx / 200, c = idx - r * 200;
            lds[r * 200 + c] = t[(base + r) * ld + 100 + c];
        }
        for (int idx = nrows * 200 + tid; idx < 16 * 200 + 16; idx += 256)
            lds[idx] = 0.f;   // kill junk beyond staged rows
        __syncthreads();
        for (int r = 0; r < nrows; ++r) {
            float va[7], zb[7];
#pragma unroll
            for (int j = 0; j < 7; ++j) va[j] = lds[r * 200 + a0 + j];
#pragma unroll
            for (int j = 0; j < 7; ++j) zb[j] = lds[r * 200 + 100 + b0 + j];
#pragma unroll
            for (int x = 0; x < 7; ++x)
#pragma unroll
                for (int y = 0; y < 7; ++y) acc[x][y] += va[x] * zb[y];
        }
    }
#pragma unroll
    for (int x = 0; x < 7; ++x)
#pragma unroll
        for (int y = 0; y < 7; ++y) {
            int a = a0 + x, b = b0 + y;
            if (a < 100 && b < 100) atomicAdd(&M[a * 100 + b], acc[x][y]);
        }
}

// ---------------- batch norm
__global__ void bn_stats(const float* __restrict__ y, int R, float* __restrict__ sums)
{
    int c = threadIdx.x;
    int i0 = blockIdx.x * 256;
    int i1 = i0 + 256; if (i1 > R) i1 = R;
    float s = 0.f, s2 = 0.f;
    for (int i = i0; i < i1; ++i) {
        float v = y[(long)i * 256 + c];
        s += v; s2 += v * v;
    }
    atomicAdd(&sums[c], s);
    atomicAdd(&sums[256 + c], s2);
}

__global__ void bn_finalize(const float* __restrict__ sums, const float* __restrict__ g,
                            const float* __restrict__ bt, int R, float* __restrict__ ab)
{
    int c = threadIdx.x;
    float mean = sums[c] / (float)R;
    float var  = sums[256 + c] / (float)R - mean * mean;
    if (var < 0.f) var = 0.f;
    float a = g[c] * rsqrtf(var + 1e-5f);
    ab[c] = a;
    ab[256 + c] = bt[c] - mean * a;
}

__global__ void bn_apply(const float* __restrict__ y, const float* __restrict__ ab,
                         int total, float* __restrict__ x)
{
    int idx = blockIdx.x * 256 + threadIdx.x;
    if (idx < total) {
        int c = idx & 255;
        x[idx] = y[idx] * ab[c] + ab[256 + c];
    }
}

// =====================================================================================
extern "C" void kernel_launch(void* const* d_in, const int* in_sizes, int n_in,
                              void* d_out, int out_size, void* d_ws, size_t ws_size,
                              hipStream_t stream)
{
    (void)n_in; (void)out_size; (void)ws_size;
    const int N = in_sizes[0] / 128;       // 50000
    const int E = in_sizes[1] / 2;         // 800000

    const float* x0  = (const float*)d_in[0];
    const int*  ei  = (const int*)d_in[1];
    const int*  esrc = ei;
    const int*  edst = ei + E;
    const float *cw[3], *cbv[3], *aw[3], *abv[3], *rw[3], *rbv[3];
    for (int l = 0; l < 3; ++l) {
        cw[l]  = (const float*)d_in[2 + 6 * l];
        cbv[l] = (const float*)d_in[3 + 6 * l];
        aw[l]  = (const float*)d_in[4 + 6 * l];
        abv[l] = (const float*)d_in[5 + 6 * l];
        rw[l]  = (const float*)d_in[6 + 6 * l];
        rbv[l] = (const float*)d_in[7 + 6 * l];
    }
    const float* g[2]   = {(const float*)d_in[20], (const float*)d_in[22]};
    const float* btb[2] = {(const float*)d_in[21], (const float*)d_in[23]};

    // ---- workspace carve (total ~166.5 MB; must stay below proven ~172 MB) ----
    char* p = (char*)d_ws;
    auto carve = [&](size_t bytes) -> char* {
        char* r = p; p += (bytes + 255) & ~(size_t)255; return r;
    };
    int*   cnt    = (int*)carve((size_t)N * 4);
    int*   rowptr = (int*)carve((size_t)(N + 1) * 4);
    int*   cursor = (int*)carve((size_t)N * 4);
    int*   colidx = (int*)carve((size_t)E * 4);
    float* dis    = (float*)carve((size_t)N * 4);
    float* Mbuf   = (float*)carve(100 * 100 * 4);
    float* csbuf  = (float*)carve(200 * 4);
    float* scale  = (float*)carve(256);
    float* bnsum  = (float*)carve(512 * 4);
    float* bnab   = (float*)carve(512 * 4);
    float* hbuf   = (float*)carve((size_t)N * 256 * 4);   // h; later y (readout output)
    float* tbuf   = (float*)carve((size_t)N * 300 * 4);   // U|V|Z; later V->T, Z->res
    float* xloc   = (float*)carve((size_t)N * 256 * 4);   // x_local; later next-layer x

    // ---- CSR build ----
    hipMemsetAsync(cnt, 0, (size_t)N * 4, stream);
    hist_kernel<<<(E + 255) / 256, 256, 0, stream>>>(edst, E, cnt);
    scan_kernel<<<1, 1024, 0, stream>>>(cnt, N, rowptr, cursor, dis);
    scatter_kernel<<<(E + 255) / 256, 256, 0, stream>>>(esrc, edst, E, cursor, colidx);

    const float* xl = x0;
    int lda = 128;
    int din[3] = {128, 256, 256};
    int dou[3] = {256, 256, 128};

    const dim3 blk(32, 8);
    auto grid = [](int cols, int rows) { return dim3((unsigned)((cols + 31) / 32), (unsigned)((rows + 7) / 8)); };

    for (int l = 0; l < 3; ++l) {
        // 1) h = x @ cw   (bias+relu deferred to aggregation)
        gemm_naive<<<grid(256, N), blk, 0, stream>>>(xl, lda, cw[l], 256, nullptr,
                                                     hbuf, 256, N, din[l], 256, 0, nullptr);
        // 2) U|V|Z = relu(x @ aw[:, :300] + ab[:300])
        gemm_naive<<<grid(300, N), blk, 0, stream>>>(xl, lda, aw[l], 400, abv[l],
                                                     tbuf, 300, N, din[l], 300, 1, nullptr);
        // 3) colsums + nf
        hipMemsetAsync(Mbuf, 0, 100 * 100 * 4, stream);
        hipMemsetAsync(csbuf, 0, 200 * 4, stream);
        colsum_kernel<<<(N + 255) / 256, 256, 0, stream>>>(tbuf, 300, N, csbuf);
        nf_kernel<<<1, 128, 0, stream>>>(csbuf, scale, N);
        // 4) M = V^T Z
        vtz_kernel<<<625, 256, 0, stream>>>(tbuf, 300, N, Mbuf);
        // 5) res = scale * (U @ M)  -> overwrite Z columns (200..299); V,Z dead after vtz
        gemm_naive<<<grid(100, N), blk, 0, stream>>>(tbuf, 300, Mbuf, 100, nullptr,
                                                     tbuf + 200, 300, N, 100, 100, 0, scale);
        // 6) T = relu(x @ aw[:, 300:400] + ab[300:]) -> overwrite V columns (100..199)
        gemm_naive<<<grid(100, N), blk, 0, stream>>>(xl, lda, aw[l] + 300, 400, abv[l] + 300,
                                                     tbuf + 100, 300, N, din[l], 100, 1, nullptr);
        // 7) x_local = relu(agg + cb)  (overwrites x; all readers of x are done)
        agg_kernel<<<(N + 3) / 4, 256, 0, stream>>>(hbuf, rowptr, colidx, dis, cbv[l],
                                                    xloc, 256, N);
        // 8) readout: y = [res | T | x_local] @ rw + rb  (y = hbuf, dead after agg)
        if (l < 2) {
            readout_kernel<<<grid(dou[l], N), blk, 0, stream>>>(tbuf, xloc, rw[l], rbv[l],
                                                                hbuf, dou[l], N, 1);
            // 9) batch norm: x_next = bn(y)  -> xloc (dead after readout)
            hipMemsetAsync(bnsum, 0, 512 * 4, stream);
            bn_stats<<<(N + 255) / 256, 256, 0, stream>>>(hbuf, N, bnsum);
            bn_finalize<<<1, 256, 0, stream>>>(bnsum, g[l], btb[l], N, bnab);
            bn_apply<<<((long)N * 256 + 255) / 256, 256, 0, stream>>>(hbuf, bnab, N * 256, xloc);
            xl = xloc; lda = 256;
        } else {
            readout_kernel<<<grid(dou[l], N), blk, 0, stream>>>(tbuf, xloc, rw[l], rbv[l],
                                                                (float*)d_out, dou[l], N, 0);
        }
    }
}

// Round 5
// 2689.299 us; speedup vs baseline: 5.1034x; 5.1034x over previous
//
#include <hip/hip_runtime.h>

typedef __bf16 bf16;
typedef __attribute__((ext_vector_type(8))) __bf16 bf16x8;
typedef __attribute__((ext_vector_type(4))) __bf16 bf16x4;
typedef __attribute__((ext_vector_type(4))) float f32x4;

// ---------------- MFMA GEMM: C[R x ncols] = A[R x Kd] * B, B given as Bt[npad x Kd] (row n = col n of B)
// 128x128 block tile, 4 waves, each wave 32 rows x 128 cols (2x8 tiles of 16x16x32), fp32 accum.
// Output: bf16 (Cb) or fp32 (Cf) per which pointer is non-null.
__global__ __launch_bounds__(256) void gemm_mfma(
    const bf16* __restrict__ A, int lda,
    const bf16* __restrict__ Bt, int Kd,
    const float* __restrict__ bias,
    bf16* __restrict__ Cb, float* __restrict__ Cf, int ldc,
    int R, int ncols, int relu,
    const float* __restrict__ scale_ptr)
{
    const int wid  = threadIdx.x >> 6;
    const int lane = threadIdx.x & 63;
    const int m    = lane & 15;
    const int quad = lane >> 4;

    const long row0    = (long)blockIdx.x * 128 + wid * 32;
    const int  colbase = blockIdx.y * 128;

    f32x4 acc[2][8];
#pragma unroll
    for (int rt = 0; rt < 2; ++rt)
#pragma unroll
        for (int ct = 0; ct < 8; ++ct)
            acc[rt][ct] = f32x4{0.f, 0.f, 0.f, 0.f};

    const bf16* Aptr[2];
#pragma unroll
    for (int rt = 0; rt < 2; ++rt) {
        long r = row0 + rt * 16 + m;
        if (r > (long)R - 1) r = (long)R - 1;   // clamp: duplicate row, stores guarded (row-separable)
        Aptr[rt] = A + r * (long)lda + quad * 8;
    }
    const bf16* Bptr[8];
#pragma unroll
    for (int ct = 0; ct < 8; ++ct) {
        long c = colbase + ct * 16 + m;         // Bt padded to gridDim.y*128 rows
        Bptr[ct] = Bt + c * (long)Kd + quad * 8;
    }

    for (int k = 0; k < Kd; k += 32) {
        bf16x8 a0 = *(const bf16x8*)(Aptr[0] + k);
        bf16x8 a1 = *(const bf16x8*)(Aptr[1] + k);
        bf16x8 b[8];
#pragma unroll
        for (int ct = 0; ct < 8; ++ct)
            b[ct] = *(const bf16x8*)(Bptr[ct] + k);
#pragma unroll
        for (int ct = 0; ct < 8; ++ct) {
            acc[0][ct] = __builtin_amdgcn_mfma_f32_16x16x32_bf16(a0, b[ct], acc[0][ct], 0, 0, 0);
            acc[1][ct] = __builtin_amdgcn_mfma_f32_16x16x32_bf16(a1, b[ct], acc[1][ct], 0, 0, 0);
        }
    }

    const float scale = scale_ptr ? *scale_ptr : 1.f;
#pragma unroll
    for (int ct = 0; ct < 8; ++ct) {
        int col = colbase + ct * 16 + m;        // C/D layout: col = lane&15
        if (col >= ncols) continue;
        float bv = bias ? bias[col] : 0.f;
#pragma unroll
        for (int rt = 0; rt < 2; ++rt) {
#pragma unroll
            for (int r = 0; r < 4; ++r) {
                long row = row0 + rt * 16 + quad * 4 + r;   // row = quad*4 + reg
                if (row < R) {
                    float v = acc[rt][ct][r] * scale + bv;
                    if (relu && v < 0.f) v = 0.f;
                    if (Cf) Cf[row * (long)ldc + col] = v;
                    else    Cb[row * (long)ldc + col] = (bf16)v;
                }
            }
        }
    }
}

// ---------------- weight transpose + cast: out[n*Kd + k] = (k<K && n<ncols) ? in[k*ncols+n] : 0
__global__ void transpose_f2b(const float* __restrict__ in, int K, int ncols,
                              bf16* __restrict__ out, int Kd, int npad)
{
    long idx = (long)blockIdx.x * 256 + threadIdx.x;
    long total = (long)npad * Kd;
    if (idx >= total) return;
    int k = (int)(idx % Kd);
    int n = (int)(idx / Kd);
    float v = (k < K && n < ncols) ? in[(long)k * ncols + n] : 0.f;
    out[idx] = (bf16)v;
}

// M (100x100 fp32) -> MT (128x128 bf16), MT[n*128+k] = M[k*100+n], zero-padded
__global__ void transpose_M(const float* __restrict__ M, bf16* __restrict__ out)
{
    int idx = blockIdx.x * 256 + threadIdx.x;   // 16384
    int k = idx & 127, n = idx >> 7;
    float v = (k < 100 && n < 100) ? M[k * 100 + n] : 0.f;
    out[idx] = (bf16)v;
}

// fp32 -> bf16 elementwise
__global__ void cast_f2b(const float* __restrict__ in, long total, bf16* __restrict__ out)
{
    long idx = (long)blockIdx.x * 256 + threadIdx.x;
    if (idx < total) out[idx] = (bf16)in[idx];
}

// ---------------- CSR build
__global__ void hist_kernel(const int* __restrict__ dst, int E, int* __restrict__ cnt)
{
    int e = blockIdx.x * 256 + threadIdx.x;
    if (e < E) atomicAdd(&cnt[dst[e]], 1);
}

__global__ __launch_bounds__(1024) void scan_kernel(const int* __restrict__ cnt, int n,
                                                    int* __restrict__ rowptr,
                                                    int* __restrict__ cursor,
                                                    float* __restrict__ dis)
{
    __shared__ int sdata[1024];
    __shared__ int s_off;
    int t = threadIdx.x;
    if (t == 0) s_off = 0;
    __syncthreads();
    for (int base = 0; base < n; base += 1024) {
        int i = base + t;
        int v = (i < n) ? cnt[i] : 0;
        sdata[t] = v;
        __syncthreads();
        for (int d = 1; d < 1024; d <<= 1) {
            int x = (t >= d) ? sdata[t - d] : 0;
            __syncthreads();
            sdata[t] += x;
            __syncthreads();
        }
        int inc = sdata[t];
        int off = s_off;
        if (i < n) {
            int excl = off + inc - v;
            rowptr[i] = excl;
            cursor[i] = excl;
            dis[i] = rsqrtf((float)(v + 1));   // deg = in-degree + self-loop
        }
        __syncthreads();
        if (t == 1023) s_off = off + inc;
        __syncthreads();
    }
    if (t == 0) rowptr[n] = s_off;
}

__global__ void scatter_kernel(const int* __restrict__ src, const int* __restrict__ dst,
                               int E, int* __restrict__ cursor, int* __restrict__ colidx)
{
    int e = blockIdx.x * 256 + threadIdx.x;
    if (e < E) {
        int d = dst[e];
        int pos = atomicAdd(&cursor[d], 1);
        colidx[pos] = src[e];
    }
}

// ---------------- GCN aggregation: one wave per dst node, bf16 h, lane covers 4 channels
__global__ __launch_bounds__(256) void agg_kernel(
    const bf16* __restrict__ h, const int* __restrict__ rowptr,
    const int* __restrict__ colidx, const float* __restrict__ dis,
    const float* __restrict__ cb, bf16* __restrict__ out, int ldc, int R)
{
    int wid = threadIdx.x >> 6, lane = threadIdx.x & 63;
    int i = blockIdx.x * 4 + wid;
    if (i >= R) return;
    float disi = dis[i];
    bf16x4 hv = *(const bf16x4*)(h + (long)i * 256 + lane * 4);
    float acc[4];
#pragma unroll
    for (int j = 0; j < 4; ++j) acc[j] = (float)hv[j] * disi;  // self loop
    int e0 = rowptr[i], e1 = rowptr[i + 1];
    for (int e = e0; e < e1; ++e) {
        int s = colidx[e];
        float w = dis[s];
        bf16x4 hs = *(const bf16x4*)(h + (long)s * 256 + lane * 4);
#pragma unroll
        for (int j = 0; j < 4; ++j) acc[j] += (float)hs[j] * w;
    }
    bf16x4 o;
#pragma unroll
    for (int j = 0; j < 4; ++j) {
        float v = acc[j] * disi + cb[lane * 4 + j];
        if (v < 0.f) v = 0.f;
        o[j] = (bf16)v;
    }
    *(bf16x4*)(out + (long)i * ldc + lane * 4) = o;
}

// ---------------- column sums of U (t cols 0..99) and V (t cols 100..199), t bf16 ld=400
__global__ void colsum_kernel(const bf16* __restrict__ t, int R, float* __restrict__ cs)
{
    int c = threadIdx.x;
    if (c >= 200) return;
    int i0 = blockIdx.x * 256;
    int i1 = i0 + 256; if (i1 > R) i1 = R;
    float s = 0.f;
    for (int i = i0; i < i1; ++i) s += (float)t[(long)i * 400 + c];
    atomicAdd(&cs[c], s);
}

__global__ void nf_kernel(const float* __restrict__ cs, float* __restrict__ scale, int R)
{
    __shared__ float s[128];
    int t = threadIdx.x;
    float v = (t < 100) ? cs[t] * cs[100 + t] : 0.f;
    s[t] = v;
    __syncthreads();
    for (int d = 64; d > 0; d >>= 1) {
        if (t < d) s[t] += s[t + d];
        __syncthreads();
    }
    if (t == 0) scale[0] = 1.0f / (s[0] / (float)R + 1e-6f);
}

// ---------------- M = V^T Z (100x100 fp32); V = t cols 100..199, Z = t cols 200..299 (bf16, ld=400)
__global__ __launch_bounds__(256) void vtz_kernel(const bf16* __restrict__ t, int R,
                                                  float* __restrict__ M)
{
    __shared__ float lds[16 * 200 + 16];
    int tid = threadIdx.x;
    int ta = tid >> 4, tb = tid & 15;
    int a0 = ta * 7, b0 = tb * 7;
    float acc[7][7] = {};
    for (long base = (long)blockIdx.x * 16; base < R; base += (long)gridDim.x * 16) {
        int nrows = (int)((R - base) < 16 ? (R - base) : 16);
        __syncthreads();
        for (int idx = tid; idx < nrows * 200; idx += 256) {
            int r = idx / 200, c = idx - r * 200;
            lds[r * 200 + c] = (float)t[(base + r) * 400 + 100 + c];
        }
        for (int idx = nrows * 200 + tid; idx < 16 * 200 + 16; idx += 256)
            lds[idx] = 0.f;
        __syncthreads();
        for (int r = 0; r < nrows; ++r) {
            float va[7], zb[7];
#pragma unroll
            for (int j = 0; j < 7; ++j) va[j] = lds[r * 200 + a0 + j];
#pragma unroll
            for (int j = 0; j < 7; ++j) zb[j] = lds[r * 200 + 100 + b0 + j];
#pragma unroll
            for (int x = 0; x < 7; ++x)
#pragma unroll
                for (int y = 0; y < 7; ++y) acc[x][y] += va[x] * zb[y];
        }
    }
#pragma unroll
    for (int x = 0; x < 7; ++x)
#pragma unroll
        for (int y = 0; y < 7; ++y) {
            int a = a0 + x, b = b0 + y;
            if (a < 100 && b < 100) atomicAdd(&M[a * 100 + b], acc[x][y]);
        }
}

// ---------------- copy T (t cols 300..399, bf16) into xcat cols 100..199 (ld=480)
__global__ void copyT_kernel(const bf16* __restrict__ t, int R, bf16* __restrict__ xcat)
{
    int idx = blockIdx.x * 256 + threadIdx.x;
    if (idx < R * 100) {
        int i = idx / 100;
        int c = idx - i * 100;
        xcat[(long)i * 480 + 100 + c] = t[(long)i * 400 + 300 + c];
    }
}

// ---------------- batch norm (y bf16, ld=256)
__global__ void bn_stats(const bf16* __restrict__ y, int R, float* __restrict__ sums)
{
    int c = threadIdx.x;
    int i0 = blockIdx.x * 256;
    int i1 = i0 + 256; if (i1 > R) i1 = R;
    float s = 0.f, s2 = 0.f;
    for (int i = i0; i < i1; ++i) {
        float v = (float)y[(long)i * 256 + c];
        s += v; s2 += v * v;
    }
    atomicAdd(&sums[c], s);
    atomicAdd(&sums[256 + c], s2);
}

__global__ void bn_finalize(const float* __restrict__ sums, const float* __restrict__ g,
                            const float* __restrict__ bt, int R, float* __restrict__ ab)
{
    int c = threadIdx.x;
    float mean = sums[c] / (float)R;
    float var  = sums[256 + c] / (float)R - mean * mean;
    if (var < 0.f) var = 0.f;
    float a = g[c] * rsqrtf(var + 1e-5f);
    ab[c] = a;
    ab[256 + c] = bt[c] - mean * a;
}

__global__ void bn_apply(const bf16* __restrict__ y, const float* __restrict__ ab,
                         int total, bf16* __restrict__ x)
{
    int idx = blockIdx.x * 256 + threadIdx.x;
    if (idx < total) {
        int c = idx & 255;
        x[idx] = (bf16)((float)y[idx] * ab[c] + ab[256 + c]);
    }
}

// =====================================================================================
extern "C" void kernel_launch(void* const* d_in, const int* in_sizes, int n_in,
                              void* d_out, int out_size, void* d_ws, size_t ws_size,
                              hipStream_t stream)
{
    (void)n_in; (void)out_size; (void)ws_size;
    const int N = in_sizes[0] / 128;       // 50000
    const int E = in_sizes[1] / 2;         // 800000

    const float* x0 = (const float*)d_in[0];
    const int*  ei   = (const int*)d_in[1];
    const int*  esrc = ei;
    const int*  edst = ei + E;
    const float *cw[3], *cbv[3], *aw[3], *abv[3], *rw[3], *rbv[3];
    for (int l = 0; l < 3; ++l) {
        cw[l]  = (const float*)d_in[2 + 6 * l];
        cbv[l] = (const float*)d_in[3 + 6 * l];
        aw[l]  = (const float*)d_in[4 + 6 * l];
        abv[l] = (const float*)d_in[5 + 6 * l];
        rw[l]  = (const float*)d_in[6 + 6 * l];
        rbv[l] = (const float*)d_in[7 + 6 * l];
    }
    const float* g[2]   = {(const float*)d_in[20], (const float*)d_in[22]};
    const float* btb[2] = {(const float*)d_in[21], (const float*)d_in[23]};

    // ---- workspace carve (~146 MB, below proven 166.5 MB) ----
    char* p = (char*)d_ws;
    auto carve = [&](size_t bytes) -> char* {
        char* r = p; p += (bytes + 255) & ~(size_t)255; return r;
    };
    int*   cnt    = (int*)carve((size_t)N * 4);
    int*   rowptr = (int*)carve((size_t)(N + 1) * 4);
    int*   cursor = (int*)carve((size_t)N * 4);
    int*   colidx = (int*)carve((size_t)E * 4);
    float* dis    = (float*)carve((size_t)N * 4);
    float* Mbuf   = (float*)carve(100 * 100 * 4);
    float* csbuf  = (float*)carve(200 * 4);
    float* scale  = (float*)carve(256);
    float* bnsum  = (float*)carve(512 * 4);
    float* bnab   = (float*)carve(512 * 4);
    bf16*  MT     = (bf16*)carve(128 * 128 * 2);
    bf16*  cwT[3], *awT[3], *rwT[3];
    int din[3] = {128, 256, 256};
    int dou[3] = {256, 256, 128};
    for (int l = 0; l < 3; ++l) {
        cwT[l] = (bf16*)carve((size_t)256 * din[l] * 2);   // 256 rows x din
        awT[l] = (bf16*)carve((size_t)512 * din[l] * 2);   // 512 rows (400 padded) x din
        rwT[l] = (bf16*)carve((size_t)dou[l] * 480 * 2);   // dou rows x 480 (456 padded)
    }
    bf16* xbf  = (bf16*)carve((size_t)N * 256 * 2);  // current x (bf16); l0 compact N x 128
    bf16* hbuf = (bf16*)carve((size_t)N * 256 * 2);  // h; later y
    bf16* tbuf = (bf16*)carve((size_t)N * 400 * 2);  // U|V|Z|T
    bf16* xcat = (bf16*)carve((size_t)N * 480 * 2);  // [res|T|xloc|pad]

    // ---- CSR build ----
    hipMemsetAsync(cnt, 0, (size_t)N * 4, stream);
    hipMemsetAsync(xcat, 0, (size_t)N * 480 * 2, stream);  // pad cols 456..479 stay 0
    hist_kernel<<<(E + 255) / 256, 256, 0, stream>>>(edst, E, cnt);
    scan_kernel<<<1, 1024, 0, stream>>>(cnt, N, rowptr, cursor, dis);
    scatter_kernel<<<(E + 255) / 256, 256, 0, stream>>>(esrc, edst, E, cursor, colidx);

    // ---- weight transposes + x0 cast ----
    for (int l = 0; l < 3; ++l) {
        transpose_f2b<<<((long)256 * din[l] + 255) / 256, 256, 0, stream>>>(
            cw[l], din[l], 256, cwT[l], din[l], 256);
        transpose_f2b<<<((long)512 * din[l] + 255) / 256, 256, 0, stream>>>(
            aw[l], din[l], 400, awT[l], din[l], 512);
        transpose_f2b<<<((long)dou[l] * 480 + 255) / 256, 256, 0, stream>>>(
            rw[l], 456, dou[l], rwT[l], 480, dou[l]);
    }
    cast_f2b<<<((long)N * 128 + 255) / 256, 256, 0, stream>>>(x0, (long)N * 128, xbf);

    int lda = 128;
    const unsigned gx = (unsigned)((N + 127) / 128);

    for (int l = 0; l < 3; ++l) {
        // 1) h = x @ cw (bias/relu deferred to agg)
        gemm_mfma<<<dim3(gx, 2), 256, 0, stream>>>(xbf, lda, cwT[l], din[l], nullptr,
                                                   hbuf, nullptr, 256, N, 256, 0, nullptr);
        // 2) U|V|Z|T = relu(x @ aw + ab)
        gemm_mfma<<<dim3(gx, 4), 256, 0, stream>>>(xbf, lda, awT[l], din[l], abv[l],
                                                   tbuf, nullptr, 400, N, 400, 1, nullptr);
        // 3) colsums + nf
        hipMemsetAsync(Mbuf, 0, 100 * 100 * 4, stream);
        hipMemsetAsync(csbuf, 0, 200 * 4, stream);
        colsum_kernel<<<(N + 255) / 256, 256, 0, stream>>>(tbuf, N, csbuf);
        nf_kernel<<<1, 128, 0, stream>>>(csbuf, scale, N);
        // 4) M = V^T Z ; cast/transpose to MT (128x128)
        vtz_kernel<<<625, 256, 0, stream>>>(tbuf, N, Mbuf);
        transpose_M<<<64, 256, 0, stream>>>(Mbuf, MT);
        // 5) res = scale * (U @ M) -> xcat cols 0..99  (K=128: A cols 100..127 junk x MT zeros)
        gemm_mfma<<<dim3(gx, 1), 256, 0, stream>>>(tbuf, 400, MT, 128, nullptr,
                                                   xcat, nullptr, 480, N, 100, 0, scale);
        // 6) T -> xcat cols 100..199
        copyT_kernel<<<((long)N * 100 + 255) / 256, 256, 0, stream>>>(tbuf, N, xcat);
        // 7) x_local = relu(agg + cb) -> xcat cols 200..455
        agg_kernel<<<(N + 3) / 4, 256, 0, stream>>>(hbuf, rowptr, colidx, dis, cbv[l],
                                                    xcat + 200, 480, N);
        // 8) readout
        if (l < 2) {
            gemm_mfma<<<dim3(gx, 2), 256, 0, stream>>>(xcat, 480, rwT[l], 480, rbv[l],
                                                       hbuf, nullptr, 256, N, 256, 1, nullptr);
            hipMemsetAsync(bnsum, 0, 512 * 4, stream);
            bn_stats<<<(N + 255) / 256, 256, 0, stream>>>(hbuf, N, bnsum);
            bn_finalize<<<1, 256, 0, stream>>>(bnsum, g[l], btb[l], N, bnab);
            bn_apply<<<((long)N * 256 + 255) / 256, 256, 0, stream>>>(hbuf, bnab, N * 256, xbf);
            lda = 256;
        } else {
            gemm_mfma<<<dim3(gx, 1), 256, 0, stream>>>(xcat, 480, rwT[l], 480, rbv[l],
                                                       nullptr, (float*)d_out, 128, N, 128, 0, nullptr);
        }
    }
}

// Round 6
// 2091.201 us; speedup vs baseline: 6.5630x; 1.2860x over previous
//
#include <hip/hip_runtime.h>

typedef __bf16 bf16;
typedef __attribute__((ext_vector_type(8))) __bf16 bf16x8;
typedef __attribute__((ext_vector_type(4))) __bf16 bf16x4;
typedef __attribute__((ext_vector_type(4))) float f32x4;

// ---------------- MFMA GEMM: C[R x ncols] = A[R x Kd] * B, B given as Bt[npad x Kd] (row n = col n of B)
// 128x128 block tile, 4 waves, each wave 32 rows x 128 cols (2x8 tiles of 16x16x32), fp32 accum.
// Output: bf16 (Cb) or fp32 (Cf) per which pointer is non-null.
__global__ __launch_bounds__(256) void gemm_mfma(
    const bf16* __restrict__ A, int lda,
    const bf16* __restrict__ Bt, int Kd,
    const float* __restrict__ bias,
    bf16* __restrict__ Cb, float* __restrict__ Cf, int ldc,
    int R, int ncols, int relu,
    const float* __restrict__ scale_ptr)
{
    const int wid  = threadIdx.x >> 6;
    const int lane = threadIdx.x & 63;
    const int m    = lane & 15;
    const int quad = lane >> 4;

    const long row0    = (long)blockIdx.x * 128 + wid * 32;
    const int  colbase = blockIdx.y * 128;

    f32x4 acc[2][8];
#pragma unroll
    for (int rt = 0; rt < 2; ++rt)
#pragma unroll
        for (int ct = 0; ct < 8; ++ct)
            acc[rt][ct] = f32x4{0.f, 0.f, 0.f, 0.f};

    const bf16* Aptr[2];
#pragma unroll
    for (int rt = 0; rt < 2; ++rt) {
        long r = row0 + rt * 16 + m;
        if (r > (long)R - 1) r = (long)R - 1;   // clamp: duplicate row, stores guarded (row-separable)
        Aptr[rt] = A + r * (long)lda + quad * 8;
    }
    const bf16* Bptr[8];
#pragma unroll
    for (int ct = 0; ct < 8; ++ct) {
        long c = colbase + ct * 16 + m;         // Bt padded to gridDim.y*128 rows
        Bptr[ct] = Bt + c * (long)Kd + quad * 8;
    }

    for (int k = 0; k < Kd; k += 32) {
        bf16x8 a0 = *(const bf16x8*)(Aptr[0] + k);
        bf16x8 a1 = *(const bf16x8*)(Aptr[1] + k);
        bf16x8 b[8];
#pragma unroll
        for (int ct = 0; ct < 8; ++ct)
            b[ct] = *(const bf16x8*)(Bptr[ct] + k);
#pragma unroll
        for (int ct = 0; ct < 8; ++ct) {
            acc[0][ct] = __builtin_amdgcn_mfma_f32_16x16x32_bf16(a0, b[ct], acc[0][ct], 0, 0, 0);
            acc[1][ct] = __builtin_amdgcn_mfma_f32_16x16x32_bf16(a1, b[ct], acc[1][ct], 0, 0, 0);
        }
    }

    const float scale = scale_ptr ? *scale_ptr : 1.f;
#pragma unroll
    for (int ct = 0; ct < 8; ++ct) {
        int col = colbase + ct * 16 + m;        // C/D layout: col = lane&15
        if (col >= ncols) continue;
        float bv = bias ? bias[col] : 0.f;
#pragma unroll
        for (int rt = 0; rt < 2; ++rt) {
#pragma unroll
            for (int r = 0; r < 4; ++r) {
                long row = row0 + rt * 16 + quad * 4 + r;   // row = quad*4 + reg
                if (row < R) {
                    float v = acc[rt][ct][r] * scale + bv;
                    if (relu && v < 0.f) v = 0.f;
                    if (Cf) Cf[row * (long)ldc + col] = v;
                    else    Cb[row * (long)ldc + col] = (bf16)v;
                }
            }
        }
    }
}

// ---------------- weight transpose + cast: out[n*Kd + k] = (k<K && n<ncols) ? in[k*ncols+n] : 0
__global__ void transpose_f2b(const float* __restrict__ in, int K, int ncols,
                              bf16* __restrict__ out, int Kd, int npad)
{
    long idx = (long)blockIdx.x * 256 + threadIdx.x;
    long total = (long)npad * Kd;
    if (idx >= total) return;
    int k = (int)(idx % Kd);
    int n = (int)(idx / Kd);
    float v = (k < K && n < ncols) ? in[(long)k * ncols + n] : 0.f;
    out[idx] = (bf16)v;
}

// M (100x100 fp32) -> MT (128x128 bf16), MT[n*128+k] = M[k*100+n], zero-padded
__global__ void transpose_M(const float* __restrict__ M, bf16* __restrict__ out)
{
    int idx = blockIdx.x * 256 + threadIdx.x;   // 16384
    int k = idx & 127, n = idx >> 7;
    float v = (k < 100 && n < 100) ? M[k * 100 + n] : 0.f;
    out[idx] = (bf16)v;
}

// fp32 -> bf16 elementwise
__global__ void cast_f2b(const float* __restrict__ in, long total, bf16* __restrict__ out)
{
    long idx = (long)blockIdx.x * 256 + threadIdx.x;
    if (idx < total) out[idx] = (bf16)in[idx];
}

// ---------------- CSR build
__global__ void hist_kernel(const int* __restrict__ dst, int E, int* __restrict__ cnt)
{
    int e = blockIdx.x * 256 + threadIdx.x;
    if (e < E) atomicAdd(&cnt[dst[e]], 1);
}

__global__ __launch_bounds__(1024) void scan_kernel(const int* __restrict__ cnt, int n,
                                                    int* __restrict__ rowptr,
                                                    int* __restrict__ cursor,
                                                    float* __restrict__ dis)
{
    __shared__ int sdata[1024];
    __shared__ int s_off;
    int t = threadIdx.x;
    if (t == 0) s_off = 0;
    __syncthreads();
    for (int base = 0; base < n; base += 1024) {
        int i = base + t;
        int v = (i < n) ? cnt[i] : 0;
        sdata[t] = v;
        __syncthreads();
        for (int d = 1; d < 1024; d <<= 1) {
            int x = (t >= d) ? sdata[t - d] : 0;
            __syncthreads();
            sdata[t] += x;
            __syncthreads();
        }
        int inc = sdata[t];
        int off = s_off;
        if (i < n) {
            int excl = off + inc - v;
            rowptr[i] = excl;
            cursor[i] = excl;
            dis[i] = rsqrtf((float)(v + 1));   // deg = in-degree + self-loop
        }
        __syncthreads();
        if (t == 1023) s_off = off + inc;
        __syncthreads();
    }
    if (t == 0) rowptr[n] = s_off;
}

__global__ void scatter_kernel(const int* __restrict__ src, const int* __restrict__ dst,
                               int E, int* __restrict__ cursor, int* __restrict__ colidx)
{
    int e = blockIdx.x * 256 + threadIdx.x;
    if (e < E) {
        int d = dst[e];
        int pos = atomicAdd(&cursor[d], 1);
        colidx[pos] = src[e];
    }
}

// ---------------- GCN aggregation: one wave per dst node, fp32 h (L3-resident), lane covers 4 channels
__global__ __launch_bounds__(256) void agg_kernel(
    const float* __restrict__ h, const int* __restrict__ rowptr,
    const int* __restrict__ colidx, const float* __restrict__ dis,
    const float* __restrict__ cb, bf16* __restrict__ out, int ldc, int R)
{
    int wid = threadIdx.x >> 6, lane = threadIdx.x & 63;
    int i = blockIdx.x * 4 + wid;
    if (i >= R) return;
    float disi = dis[i];
    f32x4 hv = *(const f32x4*)(h + (long)i * 256 + lane * 4);
    float acc[4];
#pragma unroll
    for (int j = 0; j < 4; ++j) acc[j] = hv[j] * disi;  // self loop
    int e0 = rowptr[i], e1 = rowptr[i + 1];
    for (int e = e0; e < e1; ++e) {
        int s = colidx[e];
        float w = dis[s];
        f32x4 hs = *(const f32x4*)(h + (long)s * 256 + lane * 4);
#pragma unroll
        for (int j = 0; j < 4; ++j) acc[j] += hs[j] * w;
    }
    bf16x4 o;
#pragma unroll
    for (int j = 0; j < 4; ++j) {
        float v = acc[j] * disi + cb[lane * 4 + j];
        if (v < 0.f) v = 0.f;
        o[j] = (bf16)v;
    }
    *(bf16x4*)(out + (long)i * ldc + lane * 4) = o;
}

// ---------------- column sums of U (t cols 0..99) and V (t cols 100..199), t bf16 ld=ld
__global__ void colsum_kernel(const bf16* __restrict__ t, int ld, int R, float* __restrict__ cs)
{
    int c = threadIdx.x;
    if (c >= 200) return;
    int i0 = blockIdx.x * 256;
    int i1 = i0 + 256; if (i1 > R) i1 = R;
    float s = 0.f;
    for (int i = i0; i < i1; ++i) s += (float)t[(long)i * ld + c];
    atomicAdd(&cs[c], s);
}

__global__ void nf_kernel(const float* __restrict__ cs, float* __restrict__ scale, int R)
{
    __shared__ float s[128];
    int t = threadIdx.x;
    float v = (t < 100) ? cs[t] * cs[100 + t] : 0.f;
    s[t] = v;
    __syncthreads();
    for (int d = 64; d > 0; d >>= 1) {
        if (t < d) s[t] += s[t + d];
        __syncthreads();
    }
    if (t == 0) scale[0] = 1.0f / (s[0] / (float)R + 1e-6f);
}

// ---------------- M = V^T Z stage 1: per-block partials, NO atomics.
// V = t cols 100..199, Z = t cols 200..299 (bf16, ld). Mpart[blk][a*100+b].
#define VTZ_BLOCKS 128
__global__ __launch_bounds__(256) void vtz_part(const bf16* __restrict__ t, int ld, int R,
                                                float* __restrict__ Mpart)
{
    __shared__ float lds[16 * 200 + 16];
    int tid = threadIdx.x;
    int ta = tid >> 4, tb = tid & 15;
    int a0 = ta * 7, b0 = tb * 7;
    float acc[7][7] = {};
    for (long base = (long)blockIdx.x * 16; base < R; base += (long)gridDim.x * 16) {
        int nrows = (int)((R - base) < 16 ? (R - base) : 16);
        __syncthreads();
        for (int idx = tid; idx < nrows * 200; idx += 256) {
            int r = idx / 200, c = idx - r * 200;
            lds[r * 200 + c] = (float)t[(base + r) * ld + 100 + c];
        }
        for (int idx = nrows * 200 + tid; idx < 16 * 200 + 16; idx += 256)
            lds[idx] = 0.f;
        __syncthreads();
        for (int r = 0; r < nrows; ++r) {
            float va[7], zb[7];
#pragma unroll
            for (int j = 0; j < 7; ++j) va[j] = lds[r * 200 + a0 + j];
#pragma unroll
            for (int j = 0; j < 7; ++j) zb[j] = lds[r * 200 + 100 + b0 + j];
#pragma unroll
            for (int x = 0; x < 7; ++x)
#pragma unroll
                for (int y = 0; y < 7; ++y) acc[x][y] += va[x] * zb[y];
        }
    }
    float* out = Mpart + (long)blockIdx.x * 10000;
#pragma unroll
    for (int x = 0; x < 7; ++x)
#pragma unroll
        for (int y = 0; y < 7; ++y) {
            int a = a0 + x, b = b0 + y;
            if (a < 100 && b < 100) out[a * 100 + b] = acc[x][y];
        }
}

// stage 2: M[idx] = sum over blocks of Mpart[blk][idx]
__global__ void vtz_reduce(const float* __restrict__ Mpart, float* __restrict__ M)
{
    int idx = blockIdx.x * 256 + threadIdx.x;
    if (idx >= 10000) return;
    float s = 0.f;
    for (int b = 0; b < VTZ_BLOCKS; ++b) s += Mpart[(long)b * 10000 + idx];
    M[idx] = s;
}

// ---------------- batch norm (y fp32, ld=256)
__global__ void bn_stats(const float* __restrict__ y, int R, float* __restrict__ sums)
{
    int c = threadIdx.x;
    int i0 = blockIdx.x * 256;
    int i1 = i0 + 256; if (i1 > R) i1 = R;
    float s = 0.f, s2 = 0.f;
    for (int i = i0; i < i1; ++i) {
        float v = y[(long)i * 256 + c];
        s += v; s2 += v * v;
    }
    atomicAdd(&sums[c], s);
    atomicAdd(&sums[256 + c], s2);
}

__global__ void bn_finalize(const float* __restrict__ sums, const float* __restrict__ g,
                            const float* __restrict__ bt, int R, float* __restrict__ ab)
{
    int c = threadIdx.x;
    float mean = sums[c] / (float)R;
    float var  = sums[256 + c] / (float)R - mean * mean;
    if (var < 0.f) var = 0.f;
    float a = g[c] * rsqrtf(var + 1e-5f);
    ab[c] = a;
    ab[256 + c] = bt[c] - mean * a;
}

__global__ void bn_apply(const float* __restrict__ y, const float* __restrict__ ab,
                         int total, bf16* __restrict__ x)
{
    int idx = blockIdx.x * 256 + threadIdx.x;
    if (idx < total) {
        int c = idx & 255;
        x[idx] = (bf16)(y[idx] * ab[c] + ab[256 + c]);
    }
}

// =====================================================================================
extern "C" void kernel_launch(void* const* d_in, const int* in_sizes, int n_in,
                              void* d_out, int out_size, void* d_ws, size_t ws_size,
                              hipStream_t stream)
{
    (void)n_in; (void)out_size; (void)ws_size;
    const int N = in_sizes[0] / 128;       // 50000
    const int E = in_sizes[1] / 2;         // 800000

    const float* x0 = (const float*)d_in[0];
    const int*  ei   = (const int*)d_in[1];
    const int*  esrc = ei;
    const int*  edst = ei + E;
    const float *cw[3], *cbv[3], *aw[3], *abv[3], *rw[3], *rbv[3];
    for (int l = 0; l < 3; ++l) {
        cw[l]  = (const float*)d_in[2 + 6 * l];
        cbv[l] = (const float*)d_in[3 + 6 * l];
        aw[l]  = (const float*)d_in[4 + 6 * l];
        abv[l] = (const float*)d_in[5 + 6 * l];
        rw[l]  = (const float*)d_in[6 + 6 * l];
        rbv[l] = (const float*)d_in[7 + 6 * l];
    }
    const float* g[2]   = {(const float*)d_in[20], (const float*)d_in[22]};
    const float* btb[2] = {(const float*)d_in[21], (const float*)d_in[23]};

    // ---- workspace carve (~165.5 MB, below proven-good 166.5 MB) ----
    char* p = (char*)d_ws;
    auto carve = [&](size_t bytes) -> char* {
        char* r = p; p += (bytes + 255) & ~(size_t)255; return r;
    };
    int*   cnt    = (int*)carve((size_t)N * 4);
    int*   rowptr = (int*)carve((size_t)(N + 1) * 4);
    int*   cursor = (int*)carve((size_t)N * 4);
    int*   colidx = (int*)carve((size_t)E * 4);
    float* dis    = (float*)carve((size_t)N * 4);
    float* Mbuf   = (float*)carve(100 * 100 * 4);
    float* Mpart  = (float*)carve((size_t)VTZ_BLOCKS * 10000 * 4);
    float* csbuf  = (float*)carve(200 * 4);
    float* scale  = (float*)carve(256);
    float* bnsum  = (float*)carve(512 * 4);
    float* bnab   = (float*)carve(512 * 4);
    bf16*  MT     = (bf16*)carve(128 * 128 * 2);
    bf16*  cwT[3], *awT[3], *rwT[3];
    int din[3] = {128, 256, 256};
    int dou[3] = {256, 256, 128};
    for (int l = 0; l < 3; ++l) {
        cwT[l] = (bf16*)carve((size_t)256 * din[l] * 2);   // 256 rows x din
        awT[l] = (bf16*)carve((size_t)512 * din[l] * 2);   // 512 rows (400 used) x din
        rwT[l] = (bf16*)carve((size_t)dou[l] * 480 * 2);   // dou rows x 480 (456 padded)
    }
    bf16*  xbf  = (bf16*)carve((size_t)N * 256 * 2);  // current x (bf16)
    float* hbuf = (float*)carve((size_t)N * 256 * 4); // h (fp32); later y (fp32)
    bf16*  tbuf = (bf16*)carve((size_t)N * 304 * 2);  // U|V|Z (ld=304, cols 300..303 unused)
    bf16*  xcat = (bf16*)carve((size_t)N * 480 * 2);  // [res|T|xloc|pad]

    // ---- CSR build + init ----
    hipMemsetAsync(cnt, 0, (size_t)N * 4, stream);
    hipMemsetAsync(xcat, 0, (size_t)N * 480 * 2, stream);  // pad cols 456..479 stay 0
    hist_kernel<<<(E + 255) / 256, 256, 0, stream>>>(edst, E, cnt);
    scan_kernel<<<1, 1024, 0, stream>>>(cnt, N, rowptr, cursor, dis);
    scatter_kernel<<<(E + 255) / 256, 256, 0, stream>>>(esrc, edst, E, cursor, colidx);

    // ---- weight transposes + x0 cast ----
    for (int l = 0; l < 3; ++l) {
        transpose_f2b<<<((long)256 * din[l] + 255) / 256, 256, 0, stream>>>(
            cw[l], din[l], 256, cwT[l], din[l], 256);
        transpose_f2b<<<((long)512 * din[l] + 255) / 256, 256, 0, stream>>>(
            aw[l], din[l], 400, awT[l], din[l], 512);
        transpose_f2b<<<((long)dou[l] * 480 + 255) / 256, 256, 0, stream>>>(
            rw[l], 456, dou[l], rwT[l], 480, dou[l]);
    }
    cast_f2b<<<((long)N * 128 + 255) / 256, 256, 0, stream>>>(x0, (long)N * 128, xbf);

    int lda = 128;
    const unsigned gx = (unsigned)((N + 127) / 128);

    for (int l = 0; l < 3; ++l) {
        // 1) h = x @ cw  (fp32 out; bias/relu deferred to agg)
        gemm_mfma<<<dim3(gx, 2), 256, 0, stream>>>(xbf, lda, cwT[l], din[l], nullptr,
                                                   nullptr, hbuf, 256, N, 256, 0, nullptr);
        // 2) U|V|Z = relu(x @ aw[:,0:300] + ab[0:300]) -> tbuf (ld 304)
        gemm_mfma<<<dim3(gx, 3), 256, 0, stream>>>(xbf, lda, awT[l], din[l], abv[l],
                                                   tbuf, nullptr, 304, N, 300, 1, nullptr);
        // 3) T = relu(x @ aw[:,300:400] + ab[300:]) -> xcat cols 100..199
        gemm_mfma<<<dim3(gx, 1), 256, 0, stream>>>(xbf, lda, awT[l] + (long)300 * din[l], din[l],
                                                   abv[l] + 300,
                                                   xcat + 100, nullptr, 480, N, 100, 1, nullptr);
        // 4) colsums + nf
        hipMemsetAsync(csbuf, 0, 200 * 4, stream);
        colsum_kernel<<<(N + 255) / 256, 256, 0, stream>>>(tbuf, 304, N, csbuf);
        nf_kernel<<<1, 128, 0, stream>>>(csbuf, scale, N);
        // 5) M = V^T Z  (two-stage, no atomics) ; transpose/cast to MT
        vtz_part<<<VTZ_BLOCKS, 256, 0, stream>>>(tbuf, 304, N, Mpart);
        vtz_reduce<<<40, 256, 0, stream>>>(Mpart, Mbuf);
        transpose_M<<<64, 256, 0, stream>>>(Mbuf, MT);
        // 6) res = scale * (U @ M) -> xcat cols 0..99  (K=128: A cols 100..127 (=V) x MT zero rows)
        gemm_mfma<<<dim3(gx, 1), 256, 0, stream>>>(tbuf, 304, MT, 128, nullptr,
                                                   xcat, nullptr, 480, N, 100, 0, scale);
        // 7) x_local = relu(agg + cb) -> xcat cols 200..455
        agg_kernel<<<(N + 3) / 4, 256, 0, stream>>>(hbuf, rowptr, colidx, dis, cbv[l],
                                                    xcat + 200, 480, N);
        // 8) readout
        if (l < 2) {
            gemm_mfma<<<dim3(gx, 2), 256, 0, stream>>>(xcat, 480, rwT[l], 480, rbv[l],
                                                       nullptr, hbuf, 256, N, 256, 1, nullptr);
            hipMemsetAsync(bnsum, 0, 512 * 4, stream);
            bn_stats<<<(N + 255) / 256, 256, 0, stream>>>(hbuf, N, bnsum);
            bn_finalize<<<1, 256, 0, stream>>>(bnsum, g[l], btb[l], N, bnab);
            bn_apply<<<((long)N * 256 + 255) / 256, 256, 0, stream>>>(hbuf, bnab, N * 256, xbf);
            lda = 256;
        } else {
            gemm_mfma<<<dim3(gx, 1), 256, 0, stream>>>(xcat, 480, rwT[l], 480, rbv[l],
                                                       nullptr, (float*)d_out, 128, N, 128, 0, nullptr);
        }
    }
}

// Round 7
// 1711.748 us; speedup vs baseline: 8.0179x; 1.2217x over previous
//
#include <hip/hip_runtime.h>

typedef __bf16 bf16;
typedef __attribute__((ext_vector_type(8))) __bf16 bf16x8;
typedef __attribute__((ext_vector_type(4))) __bf16 bf16x4;
typedef __attribute__((ext_vector_type(2))) __bf16 bf16x2;
typedef __attribute__((ext_vector_type(4))) float f32x4;

// ---------------- MFMA GEMM: C[R x ncols] = A[R x Kd] * B, Bt[npad x Kd] (row n = col n of B).
// 128x128 block tile, 4 waves x (2x8 tiles of 16x16x32). B-tile staged in LDS (stride 40: conflict-free).
__global__ __launch_bounds__(256) void gemm_mfma(
    const bf16* __restrict__ A, int lda,
    const bf16* __restrict__ Bt, int Kd,
    const float* __restrict__ bias,
    bf16* __restrict__ Cb, float* __restrict__ Cf, int ldc,
    int R, int ncols, int relu,
    const float* __restrict__ scale_ptr)
{
    __shared__ bf16 Bs[128 * 40];   // 10240 B
    const int tid  = threadIdx.x;
    const int wid  = tid >> 6;
    const int lane = tid & 63;
    const int m    = lane & 15;
    const int quad = lane >> 4;

    const long row0    = (long)blockIdx.x * 128 + wid * 32;
    const int  colbase = blockIdx.y * 128;

    f32x4 acc[2][8];
#pragma unroll
    for (int rt = 0; rt < 2; ++rt)
#pragma unroll
        for (int ct = 0; ct < 8; ++ct)
            acc[rt][ct] = f32x4{0.f, 0.f, 0.f, 0.f};

    const bf16* Aptr[2];
#pragma unroll
    for (int rt = 0; rt < 2; ++rt) {
        long r = row0 + rt * 16 + m;
        if (r > (long)R - 1) r = (long)R - 1;   // clamp; stores guarded (row-separable)
        Aptr[rt] = A + r * (long)lda + quad * 8;
    }
    const bf16* Bstage = Bt + ((long)colbase + (tid >> 2)) * Kd + (tid & 3) * 8;

    for (int k = 0; k < Kd; k += 32) {
        __syncthreads();
        // stage B-tile: 128 cols x 32 k; 256 threads x 2 bf16x8 each
        {
            int c = tid >> 2, kk = (tid & 3) * 8;
            *(bf16x8*)&Bs[c * 40 + kk]        = *(const bf16x8*)(Bstage + k);
            *(bf16x8*)&Bs[(c + 64) * 40 + kk] = *(const bf16x8*)(Bstage + (long)64 * Kd + k);
        }
        __syncthreads();
        bf16x8 a0 = *(const bf16x8*)(Aptr[0] + k);
        bf16x8 a1 = *(const bf16x8*)(Aptr[1] + k);
        bf16x8 b[8];
#pragma unroll
        for (int ct = 0; ct < 8; ++ct)
            b[ct] = *(const bf16x8*)&Bs[(ct * 16 + m) * 40 + quad * 8];
#pragma unroll
        for (int ct = 0; ct < 8; ++ct) {
            acc[0][ct] = __builtin_amdgcn_mfma_f32_16x16x32_bf16(a0, b[ct], acc[0][ct], 0, 0, 0);
            acc[1][ct] = __builtin_amdgcn_mfma_f32_16x16x32_bf16(a1, b[ct], acc[1][ct], 0, 0, 0);
        }
    }

    const float scale = scale_ptr ? *scale_ptr : 1.f;
#pragma unroll
    for (int ct = 0; ct < 8; ++ct) {
        int col = colbase + ct * 16 + m;        // C/D: col = lane&15
        if (col >= ncols) continue;
        float bv = bias ? bias[col] : 0.f;
#pragma unroll
        for (int rt = 0; rt < 2; ++rt) {
#pragma unroll
            for (int r = 0; r < 4; ++r) {
                long row = row0 + rt * 16 + quad * 4 + r;   // row = quad*4 + reg
                if (row < R) {
                    float v = acc[rt][ct][r] * scale + bv;
                    if (relu && v < 0.f) v = 0.f;
                    if (Cf) Cf[row * (long)ldc + col] = v;
                    else    Cb[row * (long)ldc + col] = (bf16)v;
                }
            }
        }
    }
}

// ---------------- weight transpose + cast: out[n*Kd + k] = (k<K && n<ncols) ? in[k*ncols+n] : 0
__global__ void transpose_f2b(const float* __restrict__ in, int K, int ncols,
                              bf16* __restrict__ out, int Kd, int npad)
{
    long idx = (long)blockIdx.x * 256 + threadIdx.x;
    long total = (long)npad * Kd;
    if (idx >= total) return;
    int k = (int)(idx % Kd);
    int n = (int)(idx / Kd);
    float v = (k < K && n < ncols) ? in[(long)k * ncols + n] : 0.f;
    out[idx] = (bf16)v;
}

// M (100x100 fp32) -> MT (128x128 bf16), MT[n*128+k] = M[k*100+n], zero-padded
__global__ void transpose_M(const float* __restrict__ M, bf16* __restrict__ out)
{
    int idx = blockIdx.x * 256 + threadIdx.x;   // 16384
    int k = idx & 127, n = idx >> 7;
    float v = (k < 100 && n < 100) ? M[k * 100 + n] : 0.f;
    out[idx] = (bf16)v;
}

// fp32 -> bf16 elementwise
__global__ void cast_f2b(const float* __restrict__ in, long total, bf16* __restrict__ out)
{
    long idx = (long)blockIdx.x * 256 + threadIdx.x;
    if (idx < total) out[idx] = (bf16)in[idx];
}

// ---------------- CSR build
__global__ void hist_kernel(const int* __restrict__ dst, int E, int* __restrict__ cnt)
{
    int e = blockIdx.x * 256 + threadIdx.x;
    if (e < E) atomicAdd(&cnt[dst[e]], 1);
}

__global__ __launch_bounds__(1024) void scan_kernel(const int* __restrict__ cnt, int n,
                                                    int* __restrict__ rowptr,
                                                    int* __restrict__ cursor,
                                                    float* __restrict__ dis)
{
    __shared__ int sdata[1024];
    __shared__ int s_off;
    int t = threadIdx.x;
    if (t == 0) s_off = 0;
    __syncthreads();
    for (int base = 0; base < n; base += 1024) {
        int i = base + t;
        int v = (i < n) ? cnt[i] : 0;
        sdata[t] = v;
        __syncthreads();
        for (int d = 1; d < 1024; d <<= 1) {
            int x = (t >= d) ? sdata[t - d] : 0;
            __syncthreads();
            sdata[t] += x;
            __syncthreads();
        }
        int inc = sdata[t];
        int off = s_off;
        if (i < n) {
            int excl = off + inc - v;
            rowptr[i] = excl;
            cursor[i] = excl;
            dis[i] = rsqrtf((float)(v + 1));   // deg = in-degree + self-loop
        }
        __syncthreads();
        if (t == 1023) s_off = off + inc;
        __syncthreads();
    }
    if (t == 0) rowptr[n] = s_off;
}

__global__ void scatter_kernel(const int* __restrict__ src, const int* __restrict__ dst,
                               int E, int* __restrict__ cursor, int* __restrict__ colidx)
{
    int e = blockIdx.x * 256 + threadIdx.x;
    if (e < E) {
        int d = dst[e];
        int pos = atomicAdd(&cursor[d], 1);
        colidx[pos] = src[e];
    }
}

// ---------------- GCN aggregation: one wave per dst node, fp32 h (L2/L3-resident)
__global__ __launch_bounds__(256) void agg_kernel(
    const float* __restrict__ h, const int* __restrict__ rowptr,
    const int* __restrict__ colidx, const float* __restrict__ dis,
    const float* __restrict__ cb, bf16* __restrict__ out, int ldc, int R)
{
    int wid = threadIdx.x >> 6, lane = threadIdx.x & 63;
    int i = blockIdx.x * 4 + wid;
    if (i >= R) return;
    float disi = dis[i];
    f32x4 hv = *(const f32x4*)(h + (long)i * 256 + lane * 4);
    float acc[4];
#pragma unroll
    for (int j = 0; j < 4; ++j) acc[j] = hv[j] * disi;  // self loop
    int e0 = rowptr[i], e1 = rowptr[i + 1];
    for (int e = e0; e < e1; ++e) {
        int s = colidx[e];
        float w = dis[s];
        f32x4 hs = *(const f32x4*)(h + (long)s * 256 + lane * 4);
#pragma unroll
        for (int j = 0; j < 4; ++j) acc[j] += hs[j] * w;
    }
    bf16x4 o;
#pragma unroll
    for (int j = 0; j < 4; ++j) {
        float v = acc[j] * disi + cb[lane * 4 + j];
        if (v < 0.f) v = 0.f;
        o[j] = (bf16)v;
    }
    *(bf16x4*)(out + (long)i * ldc + lane * 4) = o;
}

// ---------------- column sums of U (t cols 0..99) and V (t cols 100..199)
__global__ void colsum_kernel(const bf16* __restrict__ t, int ld, int R, float* __restrict__ cs)
{
    int c = threadIdx.x;
    if (c >= 200) return;
    int i0 = blockIdx.x * 256;
    int i1 = i0 + 256; if (i1 > R) i1 = R;
    float s = 0.f;
    for (int i = i0; i < i1; ++i) s += (float)t[(long)i * ld + c];
    atomicAdd(&cs[c], s);
}

__global__ void nf_kernel(const float* __restrict__ cs, float* __restrict__ scale, int R)
{
    __shared__ float s[128];
    int t = threadIdx.x;
    float v = (t < 100) ? cs[t] * cs[100 + t] : 0.f;
    s[t] = v;
    __syncthreads();
    for (int d = 64; d > 0; d >>= 1) {
        if (t < d) s[t] += s[t + d];
        __syncthreads();
    }
    if (t == 0) scale[0] = 1.0f / (s[0] / (float)R + 1e-6f);
}

// ---------------- M = V^T Z via MFMA. V = t cols 100..199, Z = t cols 200..299 (bf16, ld).
// Per block: 64-row chunks staged transposed in LDS (stride 72 -> 2-way bank alias, free),
// 112x112 output as 7x7 tiles of 16x16x32, fp32 partials, no atomics.
#define VTZ_BLOCKS 128
__global__ __launch_bounds__(256) void vtz_mfma(const bf16* __restrict__ t, int ld, int R,
                                                float* __restrict__ Mpart)
{
    __shared__ bf16 Vt[112 * 72];
    __shared__ bf16 Zt[112 * 72];
    const int tid  = threadIdx.x;
    const int wid  = tid >> 6;
    const int lane = tid & 63;
    const int m    = lane & 15;
    const int quad = lane >> 4;

    // zero pad rows c = 100..111 once (never rewritten)
    for (int idx = tid; idx < 12 * 64; idx += 256) {
        int c = 100 + (idx >> 6), r = idx & 63;
        Vt[c * 72 + r] = (bf16)0.f;
        Zt[c * 72 + r] = (bf16)0.f;
    }

    f32x4 acc[2][7];
#pragma unroll
    for (int rt = 0; rt < 2; ++rt)
#pragma unroll
        for (int ct = 0; ct < 7; ++ct)
            acc[rt][ct] = f32x4{0.f, 0.f, 0.f, 0.f};

    for (long base = (long)blockIdx.x * 64; base < R; base += (long)gridDim.x * 64) {
        __syncthreads();
        // stage V,Z transposed: 50 cols-pairs x 64 rows each; bf16x2 global reads
        for (int idx = tid; idx < 50 * 64; idx += 256) {
            int r = idx / 50, c2 = (idx - r * 50) * 2;
            bf16x2 v2 = bf16x2{(bf16)0.f, (bf16)0.f};
            bf16x2 z2 = bf16x2{(bf16)0.f, (bf16)0.f};
            if (base + r < R) {
                v2 = *(const bf16x2*)(t + (base + r) * ld + 100 + c2);
                z2 = *(const bf16x2*)(t + (base + r) * ld + 200 + c2);
            }
            Vt[c2 * 72 + r] = v2[0]; Vt[(c2 + 1) * 72 + r] = v2[1];
            Zt[c2 * 72 + r] = z2[0]; Zt[(c2 + 1) * 72 + r] = z2[1];
        }
        __syncthreads();
#pragma unroll
        for (int ks = 0; ks < 2; ++ks) {
            int k0 = ks * 32 + quad * 8;
            bf16x8 b[7];
#pragma unroll
            for (int ct = 0; ct < 7; ++ct)
                b[ct] = *(const bf16x8*)&Zt[(ct * 16 + m) * 72 + k0];
#pragma unroll
            for (int rt = 0; rt < 2; ++rt) {
                int tr = wid + rt * 4;
                if (tr >= 7) continue;
                bf16x8 a = *(const bf16x8*)&Vt[(tr * 16 + m) * 72 + k0];
#pragma unroll
                for (int ct = 0; ct < 7; ++ct)
                    acc[rt][ct] = __builtin_amdgcn_mfma_f32_16x16x32_bf16(a, b[ct], acc[rt][ct], 0, 0, 0);
            }
        }
    }

    float* out = Mpart + (long)blockIdx.x * 10000;
#pragma unroll
    for (int rt = 0; rt < 2; ++rt) {
        int tr = wid + rt * 4;
        if (tr >= 7) continue;
#pragma unroll
        for (int ct = 0; ct < 7; ++ct) {
            int b = ct * 16 + m;               // col = lane&15
            if (b >= 100) continue;
#pragma unroll
            for (int r = 0; r < 4; ++r) {
                int a = tr * 16 + quad * 4 + r; // row = quad*4 + reg
                if (a < 100) out[a * 100 + b] = acc[rt][ct][r];
            }
        }
    }
}

// stage 2: M[idx] = sum over blocks of Mpart[blk][idx]
__global__ void vtz_reduce(const float* __restrict__ Mpart, float* __restrict__ M)
{
    int idx = blockIdx.x * 256 + threadIdx.x;
    if (idx >= 10000) return;
    float s = 0.f;
    for (int b = 0; b < VTZ_BLOCKS; ++b) s += Mpart[(long)b * 10000 + idx];
    M[idx] = s;
}

// ---------------- batch norm (y fp32, ld=256)
__global__ void bn_stats(const float* __restrict__ y, int R, float* __restrict__ sums)
{
    int c = threadIdx.x;
    int i0 = blockIdx.x * 256;
    int i1 = i0 + 256; if (i1 > R) i1 = R;
    float s = 0.f, s2 = 0.f;
    for (int i = i0; i < i1; ++i) {
        float v = y[(long)i * 256 + c];
        s += v; s2 += v * v;
    }
    atomicAdd(&sums[c], s);
    atomicAdd(&sums[256 + c], s2);
}

__global__ void bn_finalize(const float* __restrict__ sums, const float* __restrict__ g,
                            const float* __restrict__ bt, int R, float* __restrict__ ab)
{
    int c = threadIdx.x;
    float mean = sums[c] / (float)R;
    float var  = sums[256 + c] / (float)R - mean * mean;
    if (var < 0.f) var = 0.f;
    float a = g[c] * rsqrtf(var + 1e-5f);
    ab[c] = a;
    ab[256 + c] = bt[c] - mean * a;
}

__global__ void bn_apply(const float* __restrict__ y, const float* __restrict__ ab,
                         int total, bf16* __restrict__ x)
{
    int idx = blockIdx.x * 256 + threadIdx.x;
    if (idx < total) {
        int c = idx & 255;
        x[idx] = (bf16)(y[idx] * ab[c] + ab[256 + c]);
    }
}

// =====================================================================================
extern "C" void kernel_launch(void* const* d_in, const int* in_sizes, int n_in,
                              void* d_out, int out_size, void* d_ws, size_t ws_size,
                              hipStream_t stream)
{
    (void)n_in; (void)out_size; (void)ws_size;
    const int N = in_sizes[0] / 128;       // 50000
    const int E = in_sizes[1] / 2;         // 800000

    const float* x0 = (const float*)d_in[0];
    const int*  ei   = (const int*)d_in[1];
    const int*  esrc = ei;
    const int*  edst = ei + E;
    const float *cw[3], *cbv[3], *aw[3], *abv[3], *rw[3], *rbv[3];
    for (int l = 0; l < 3; ++l) {
        cw[l]  = (const float*)d_in[2 + 6 * l];
        cbv[l] = (const float*)d_in[3 + 6 * l];
        aw[l]  = (const float*)d_in[4 + 6 * l];
        abv[l] = (const float*)d_in[5 + 6 * l];
        rw[l]  = (const float*)d_in[6 + 6 * l];
        rbv[l] = (const float*)d_in[7 + 6 * l];
    }
    const float* g[2]   = {(const float*)d_in[20], (const float*)d_in[22]};
    const float* btb[2] = {(const float*)d_in[21], (const float*)d_in[23]};

    // ---- workspace carve (~163 MB, below proven-good 166.5 MB) ----
    char* p = (char*)d_ws;
    auto carve = [&](size_t bytes) -> char* {
        char* r = p; p += (bytes + 255) & ~(size_t)255; return r;
    };
    int*   cnt    = (int*)carve((size_t)N * 4);
    int*   rowptr = (int*)carve((size_t)(N + 1) * 4);
    int*   cursor = (int*)carve((size_t)N * 4);
    int*   colidx = (int*)carve((size_t)E * 4);
    float* dis    = (float*)carve((size_t)N * 4);
    float* Mbuf   = (float*)carve(100 * 100 * 4);
    float* Mpart  = (float*)carve((size_t)VTZ_BLOCKS * 10000 * 4);
    float* csbuf  = (float*)carve(200 * 4);
    float* scale  = (float*)carve(256);
    float* bnsum  = (float*)carve(512 * 4);
    float* bnab   = (float*)carve(512 * 4);
    bf16*  MT     = (bf16*)carve(128 * 128 * 2);
    bf16*  cwT[3], *awT[3], *rwT[3];
    int din[3] = {128, 256, 256};
    int dou[3] = {256, 256, 128};
    for (int l = 0; l < 3; ++l) {
        cwT[l] = (bf16*)carve((size_t)256 * din[l] * 2);   // 256 rows x din
        awT[l] = (bf16*)carve((size_t)512 * din[l] * 2);   // 512 rows (400 used) x din
        rwT[l] = (bf16*)carve((size_t)dou[l] * 480 * 2);   // dou rows x 480 (456 zero-padded)
    }
    bf16*  xbf  = (bf16*)carve((size_t)N * 256 * 2);        // current x (bf16)
    float* hbuf = (float*)carve((size_t)N * 256 * 4);       // h (fp32); later y (fp32)
    bf16*  tbuf = (bf16*)carve((size_t)N * 300 * 2);        // U|V|Z (ld=300)
    bf16*  xcat = (bf16*)carve(((size_t)N * 456 + 32) * 2); // [res|T|xloc], ld=456 (+K-pad slack)

    // ---- CSR build ----
    hipMemsetAsync(cnt, 0, (size_t)N * 4, stream);
    hist_kernel<<<(E + 255) / 256, 256, 0, stream>>>(edst, E, cnt);
    scan_kernel<<<1, 1024, 0, stream>>>(cnt, N, rowptr, cursor, dis);
    scatter_kernel<<<(E + 255) / 256, 256, 0, stream>>>(esrc, edst, E, cursor, colidx);

    // ---- weight transposes + x0 cast ----
    for (int l = 0; l < 3; ++l) {
        transpose_f2b<<<((long)256 * din[l] + 255) / 256, 256, 0, stream>>>(
            cw[l], din[l], 256, cwT[l], din[l], 256);
        transpose_f2b<<<((long)512 * din[l] + 255) / 256, 256, 0, stream>>>(
            aw[l], din[l], 400, awT[l], din[l], 512);
        transpose_f2b<<<((long)dou[l] * 480 + 255) / 256, 256, 0, stream>>>(
            rw[l], 456, dou[l], rwT[l], 480, dou[l]);
    }
    cast_f2b<<<((long)N * 128 + 255) / 256, 256, 0, stream>>>(x0, (long)N * 128, xbf);

    int lda = 128;
    const unsigned gx = (unsigned)((N + 127) / 128);

    for (int l = 0; l < 3; ++l) {
        // 1) h = x @ cw  (fp32 out; bias/relu deferred to agg)
        gemm_mfma<<<dim3(gx, 2), 256, 0, stream>>>(xbf, lda, cwT[l], din[l], nullptr,
                                                   nullptr, hbuf, 256, N, 256, 0, nullptr);
        // 2) U|V|Z = relu(x @ aw[:,0:300] + ab[0:300]) -> tbuf (ld 300)
        gemm_mfma<<<dim3(gx, 3), 256, 0, stream>>>(xbf, lda, awT[l], din[l], abv[l],
                                                   tbuf, nullptr, 300, N, 300, 1, nullptr);
        // 3) T = relu(x @ aw[:,300:400] + ab[300:]) -> xcat cols 100..199
        gemm_mfma<<<dim3(gx, 1), 256, 0, stream>>>(xbf, lda, awT[l] + (long)300 * din[l], din[l],
                                                   abv[l] + 300,
                                                   xcat + 100, nullptr, 456, N, 100, 1, nullptr);
        // 4) colsums + nf
        hipMemsetAsync(csbuf, 0, 200 * 4, stream);
        colsum_kernel<<<(N + 255) / 256, 256, 0, stream>>>(tbuf, 300, N, csbuf);
        nf_kernel<<<1, 128, 0, stream>>>(csbuf, scale, N);
        // 5) M = V^T Z (MFMA two-stage, no atomics) ; transpose/cast to MT
        vtz_mfma<<<VTZ_BLOCKS, 256, 0, stream>>>(tbuf, 300, N, Mpart);
        vtz_reduce<<<40, 256, 0, stream>>>(Mpart, Mbuf);
        transpose_M<<<64, 256, 0, stream>>>(Mbuf, MT);
        // 6) res = scale * (U @ M) -> xcat cols 0..99  (Kd=128: A cols 100..127 (=V) x MT zero rows)
        gemm_mfma<<<dim3(gx, 1), 256, 0, stream>>>(tbuf, 300, MT, 128, nullptr,
                                                   xcat, nullptr, 456, N, 100, 0, scale);
        // 7) x_local = relu(agg + cb) -> xcat cols 200..455
        agg_kernel<<<(N + 3) / 4, 256, 0, stream>>>(hbuf, rowptr, colidx, dis, cbv[l],
                                                    xcat + 200, 456, N);
        // 8) readout: Kd=480 reads xcat cols 456..479 = next-row junk x zero weight rows = 0
        if (l < 2) {
            gemm_mfma<<<dim3(gx, 2), 256, 0, stream>>>(xcat, 456, rwT[l], 480, rbv[l],
                                                       nullptr, hbuf, 256, N, 256, 1, nullptr);
            hipMemsetAsync(bnsum, 0, 512 * 4, stream);
            bn_stats<<<(N + 255) / 256, 256, 0, stream>>>(hbuf, N, bnsum);
            bn_finalize<<<1, 256, 0, stream>>>(bnsum, g[l], btb[l], N, bnab);
            bn_apply<<<((long)N * 256 + 255) / 256, 256, 0, stream>>>(hbuf, bnab, N * 256, xbf);
            lda = 256;
        } else {
            gemm_mfma<<<dim3(gx, 1), 256, 0, stream>>>(xcat, 456, rwT[l], 480, rbv[l],
                                                       nullptr, (float*)d_out, 128, N, 128, 0, nullptr);
        }
    }
}